// Round 10
// baseline (64.586 us; speedup 1.0000x reference)
//
#include <hip/hip_runtime.h>

typedef unsigned long long u64;
typedef unsigned int u32;

#define HH 512
#define WW 512
#define BATCH 32
#define NPIX (BATCH*HH*WW)
#define NWORDS (NPIX/64)
#define WPI (HH*WW/64)      /* u64 words per image = 4096 */
#define WPR (WW/64)         /* u64 words per row = 8 */

#define PS_BLOCKS (BATCH*16)       /* 512: one 32-row strip each */
#define MAIN_BLOCKS 2048           /* 16 px/thread */
#define MAIN_THREADS 256
#define WINMASK ((((1ULL<<49)-1)) << 8)   /* dx in [-24,24] of the 64-bit window */

/* workspace layout (bytes) */
#define WS_MAINP  0          /* double mainP[MAIN_BLOCKS*6] = 96 KiB */
#define WS_TBITS  262144     /* u64[NWORDS] = 1 MiB */
#define WS_BMBITS 1310720    /* u64[NWORDS] = 1 MiB */

__device__ __forceinline__ float hw_exp2(float x) { return __builtin_amdgcn_exp2f(x); }
__device__ __forceinline__ float hw_log2(float x) { return __builtin_amdgcn_logf(x); }

// ============ fused pack + stencil ============
__global__ __launch_bounds__(256) void pack_stencil_kernel(
        const float4* __restrict__ t4, u64* __restrict__ tbits,
        u64* __restrict__ bmbits) {
    __shared__ u64 lw[36][9];          /* 72B row stride (9th word = pad) */

    const int blk = blockIdx.x;
    const int img = blk >> 4;
    const int strip = blk & 15;
    const int row0 = strip * 32;

    unsigned char* lb = (unsigned char*)lw;
    #pragma unroll
    for (int it = 0; it < 9; ++it) {
        int i = it * 256 + threadIdx.x;    /* 0..2303: 36 rows x 64 bytes */
        int r = i >> 6, c = i & 63;
        int gy = row0 - 2 + r;
        unsigned b = 0;
        if (gy >= 0 && gy < HH) {
            int base = img * (HH*WW/4) + gy * (WW/4) + c * 2;
            float4 lo = t4[base], hi = t4[base + 1];
            b =  (lo.x > 0.5f)       | ((lo.y > 0.5f) << 1)
              | ((lo.z > 0.5f) << 2) | ((lo.w > 0.5f) << 3)
              | ((hi.x > 0.5f) << 4) | ((hi.y > 0.5f) << 5)
              | ((hi.z > 0.5f) << 6) | ((hi.w > 0.5f) << 7);
        }
        lb[r * 72 + c] = (unsigned char)b;
    }
    __syncthreads();

    const int r  = threadIdx.x >> 3;   /* 0..31 owned row */
    const int wc = threadIdx.x & 7;    /* 0..7 word col   */

    u64 w[5][5];
    #pragma unroll
    for (int dr = 0; dr < 5; ++dr)
        #pragma unroll
        for (int dc = 0; dc < 5; ++dc) {
            int cc = wc + dc - 2;
            w[dr][dc] = (cc >= 0 && cc < 8) ? lw[r + dr][cc] : 0ULL;
        }

    u64 ha[5][3];
    #pragma unroll
    for (int rr = 0; rr < 5; ++rr)
        #pragma unroll
        for (int j = 0; j < 3; ++j) {
            u64 C = w[rr][j + 1], L = w[rr][j], R = w[rr][j + 2];
            ha[rr][j] = ((C << 1) | (L >> 63)) & C & ((C >> 1) | (R << 63));
        }

    u64 eg[3][3];
    #pragma unroll
    for (int i = 0; i < 3; ++i)
        #pragma unroll
        for (int j = 0; j < 3; ++j) {
            u64 er = ha[i][j] & ha[i + 1][j] & ha[i + 2][j];
            eg[i][j] = w[i + 1][j + 1] & ~er;
        }

    u64 out = 0ULL;
    #pragma unroll
    for (int i = 0; i < 3; ++i) {
        u64 E = eg[i][1], L = eg[i][0], R = eg[i][2];
        out |= ((E << 1) | (L >> 63)) | E | ((E >> 1) | (R << 63));
    }

    int gw = img * WPI + (row0 + r) * WPR + wc;
    tbits[gw]  = w[2][2];
    bmbits[gw] = out;
}

// nearest set-bit horizontal distance within +/-24 of x0 on one bit-packed row; 99 if none
__device__ __forceinline__ int rowscan(const u64* __restrict__ row, int x0) {
    int s = x0 - 32;
    int wi = s >> 6;
    int sh = s & 63;
    u64 lo = (wi >= 0 && wi < WPR) ? row[wi] : 0ULL;
    u64 hi = ((wi + 1) < WPR) ? row[wi + 1] : 0ULL;
    u64 win = sh ? ((lo >> sh) | (hi << (64 - sh))) : lo;
    win &= WINMASK;
    u64 left = win << 32;
    u64 right = win >> 32;
    int dl = left ? (__builtin_clzll(left) + 1) : 99;
    int dr = right ? __builtin_ctzll(right) : 99;
    return dl < dr ? dl : dr;
}

// full chamfer weight for one non-boundary pixel
__device__ __forceinline__ float search_weight(const u64* __restrict__ img, int pix) {
    const float L2E = 1.44269504f;
    int x0 = pix & (WW - 1);
    int y0 = (pix >> 9) & (HH - 1);
    float best = 1e9f;
    for (int ady = 0; ady <= 24; ++ady) {
        if ((float)ady >= best) break;
        int hd = 99;
        int yU = y0 - ady;
        if (yU >= 0) hd = rowscan(img + yU * WPR, x0);
        int yD = y0 + ady;
        if (ady > 0 && yD < HH) {
            int h2 = rowscan(img + yD * WPR, x0);
            hd = h2 < hd ? h2 : hd;
        }
        if (hd <= 24) {
            float h = (float)hd, ay = (float)ady;
            float mx = fmaxf(h, ay), mn = fminf(h, ay);
            best = fminf(best, mx + 0.4142135f * mn);
        }
    }
    return (best < 1e8f) ? (hw_exp2(best * (-L2E / 3.0f)) + 0.1f) : 0.1f;
}

// ============ streaming reductions + per-lane deferred search ============
// 16 consecutive px per thread (one 16-bit slice of a u64 word).
__global__ __launch_bounds__(MAIN_THREADS, 6) void main_kernel(
        const float4* __restrict__ x4, const float* __restrict__ x,
        const u64* __restrict__ tbits, const u64* __restrict__ bmbits,
        const float* __restrict__ alpha_p, const float* __restrict__ gamma_p,
        double* __restrict__ mainP) {
    __shared__ double red[4][6];

    const float a = fminf(fmaxf(alpha_p[0], 0.1f), 0.9f);
    const float one_m_a = 1.0f - a;
    const float g = fminf(fmaxf(gamma_p[0], 1.0f), 5.0f);
    const float gr = rintf(g);
    const bool gint = (g == gr);
    const int gi = (int)gr;
    const float LOGCLIP = 16.11809565f;   // -log(1e-7)
    const float L2E = 1.44269504f;
    const float LN2 = 0.69314718f;

    const int q16 = blockIdx.x * MAIN_THREADS + threadIdx.x;   /* 16px-group id */
    const int pix0 = q16 * 16;
    const int subsh = (q16 & 3) * 16;
    const u64 tw = tbits[q16 >> 2] >> subsh;     /* low 16 bits valid */
    const u64 bw = bmbits[q16 >> 2] >> subsh;
    const u64* img = bmbits + (pix0 >> 18) * WPI;

    float4 xv[4];
    #pragma unroll
    for (int j = 0; j < 4; ++j) xv[j] = x4[q16 * 4 + j];

    float s_p = 0.f, s_pt = 0.f, s_f = 0.f, s_b = 0.f, s_bnd_bm = 0.f, s_bnd_q = 0.f;
    int c_t = 0;
    int cnt = 0;
    u32 klist = 0;

    #pragma unroll
    for (int j = 0; j < 4; ++j) {
        float xs[4] = {xv[j].x, xv[j].y, xv[j].z, xv[j].w};
        #pragma unroll
        for (int kk = 0; kk < 4; ++kk) {
            const int k = j * 4 + kk;
            float xvv = xs[kk];
            int tb = (int)((tw >> k) & 1ULL);
            int bm = (int)((bw >> k) & 1ULL);

            float ax = fabsf(xvv);
            float e  = hw_exp2(ax * -L2E);             // exp(-|x|)
            float rc = __builtin_amdgcn_rcpf(1.0f + e);
            float p  = (xvv >= 0.0f) ? rc : e * rc;    // sigmoid
            float l1pe = hw_log2(1.0f + e) * LN2;      // log(1+exp(-|x|))
            float sp_neg = fmaxf(-xvv, 0.0f) + l1pe;   // softplus(-x)
            float sp_pos = sp_neg + xvv;               // softplus(x)

            float bce_el = sp_neg + (tb ? 0.025f : 0.975f) * xvv;
            float q95 = 0.95f * p;
            float u   = tb ? (0.975f - q95) : (0.025f + q95);   // 1 - p_t
            float a_t = tb ? a : one_m_a;
            float pw;
            if (gint) {
                float u2 = u * u;
                pw = (gi == 1) ? u : (gi == 2) ? u2 : (gi == 3) ? u2 * u
                   : (gi == 4) ? u2 * u2 : u2 * u2 * u;
            } else {
                pw = hw_exp2(g * hw_log2(u));
            }
            float focal_el = a_t * pw * bce_el;

            float bce2 = tb ? 7.0f * sp_neg : sp_pos;
            float bnd  = fminf(tb ? sp_neg : sp_pos, LOGCLIP);

            if (bm) {
                s_bnd_bm += bnd;                       /* d=0 -> w=1.1, applied later */
            } else if (cnt < 4) {
                klist |= (u32)k << (4 * cnt);          /* defer: 4-bit px index */
                ++cnt;
            } else {
                /* overflow (P ~ 1e-4): search inline, bnd already live */
                s_bnd_q += bnd * search_weight(img, pix0 + k);
            }

            s_p  += p;
            c_t  += tb;
            s_pt += tb ? p : 0.0f;
            s_f  += focal_el;
            s_b  += bce2;
        }
    }

    /* drain deferred searchers (wave-max ~3-4 searches, paid once) */
    #pragma unroll
    for (int j = 0; j < 4; ++j) {
        if (j < cnt) {
            int k = (int)((klist >> (4 * j)) & 15u);
            int pix = pix0 + k;
            float xvv = x[pix];                        /* L1-hot reload */
            int tb = (int)((tw >> k) & 1ULL);
            float ax = fabsf(xvv);
            float e = hw_exp2(ax * -L2E);
            float l1pe = hw_log2(1.0f + e) * LN2;
            float sp_neg = fmaxf(-xvv, 0.0f) + l1pe;
            float sp = tb ? sp_neg : (sp_neg + xvv);
            float bnd = fminf(sp, LOGCLIP);
            s_bnd_q += bnd * search_weight(img, pix);
        }
    }

    double d_p = s_p, d_t = (double)c_t, d_pt = s_pt, d_f = s_f, d_b = s_b;
    double d_bnd = (double)s_bnd_bm * 1.1 + (double)s_bnd_q;

    #pragma unroll
    for (int off = 32; off > 0; off >>= 1) {
        d_p   += __shfl_down(d_p, off);
        d_t   += __shfl_down(d_t, off);
        d_pt  += __shfl_down(d_pt, off);
        d_f   += __shfl_down(d_f, off);
        d_b   += __shfl_down(d_b, off);
        d_bnd += __shfl_down(d_bnd, off);
    }

    int lane = threadIdx.x & 63, wid = threadIdx.x >> 6;
    if (lane == 0) {
        red[wid][0] = d_p;  red[wid][1] = d_t;  red[wid][2] = d_pt;
        red[wid][3] = d_f;  red[wid][4] = d_b;  red[wid][5] = d_bnd;
    }
    __syncthreads();
    if (threadIdx.x == 0) {
        #pragma unroll
        for (int i = 0; i < 6; ++i)
            mainP[blockIdx.x * 6 + i] = red[0][i] + red[1][i] + red[2][i] + red[3][i];
    }
}

// ============ final reduction + loss assembly ============
__global__ __launch_bounds__(256) void reduce_kernel(const double* __restrict__ mainP,
                                                     float* __restrict__ out) {
    double s[6] = {0, 0, 0, 0, 0, 0};
    for (int b = threadIdx.x; b < MAIN_BLOCKS; b += 256)
        #pragma unroll
        for (int i = 0; i < 6; ++i) s[i] += mainP[b * 6 + i];

    #pragma unroll
    for (int off = 32; off > 0; off >>= 1)
        #pragma unroll
        for (int i = 0; i < 6; ++i) s[i] += __shfl_down(s[i], off);

    __shared__ double red[4][6];
    int lane = threadIdx.x & 63, wid = threadIdx.x >> 6;
    if (lane == 0)
        #pragma unroll
        for (int i = 0; i < 6; ++i) red[wid][i] = s[i];
    __syncthreads();

    if (threadIdx.x == 0) {
        double S_p = red[0][0] + red[1][0] + red[2][0] + red[3][0];
        double S_t = red[0][1] + red[1][1] + red[2][1] + red[3][1];
        double S_pt = red[0][2] + red[1][2] + red[2][2] + red[3][2];
        double S_f = red[0][3] + red[1][3] + red[2][3] + red[3][3];
        double S_b = red[0][4] + red[1][4] + red[2][4] + red[3][4];
        double S_bnd = red[0][5] + red[1][5] + red[2][5] + red[3][5];
        const double N = (double)NPIX;
        double inter = S_pt;
        double card = S_p + S_t;
        double dice_score = (2.0 * inter + 1e-6) / fmax(card + 1e-6, 1e-7);
        double dice = (S_t > 0.0) ? (1.0 - dice_score) : 0.0;
        double focal = S_f / N;
        double bce = S_b / N;
        double pos_ratio = S_t / N;
        double da = 0.7 * (1.0 + pos_ratio);
        double db = 0.3 * (2.0 - pos_ratio);
        double fn = S_t - S_pt;
        double fp = (S_p - S_pt) * 3.0;
        double tversky = 1.0 - (S_pt + 1e-6) / (S_pt + da * fn + db * fp + 1e-6);
        double bnd = S_bnd / N;
        out[0] = (float)(0.35 * dice + 0.25 * focal + 0.15 * bce + 0.15 * tversky + 0.1 * bnd);
    }
}

extern "C" void kernel_launch(void* const* d_in, const int* in_sizes, int n_in,
                              void* d_out, int out_size, void* d_ws, size_t ws_size,
                              hipStream_t stream) {
    const float* inputs  = (const float*)d_in[0];
    const float* targets = (const float*)d_in[1];
    const float* alpha_p = (const float*)d_in[2];
    const float* gamma_p = (const float*)d_in[3];
    float* out = (float*)d_out;

    char* ws = (char*)d_ws;
    double* mainP   = (double*)(ws + WS_MAINP);
    u64*    tbits   = (u64*)(ws + WS_TBITS);
    u64*    bmbits  = (u64*)(ws + WS_BMBITS);

    pack_stencil_kernel<<<PS_BLOCKS, 256, 0, stream>>>(
        (const float4*)targets, tbits, bmbits);

    main_kernel<<<MAIN_BLOCKS, MAIN_THREADS, 0, stream>>>(
        (const float4*)inputs, inputs, tbits, bmbits, alpha_p, gamma_p, mainP);

    reduce_kernel<<<1, 256, 0, stream>>>(mainP, out);
}

// Round 11
// 42.821 us; speedup vs baseline: 1.5083x; 1.5083x over previous
//
#include <hip/hip_runtime.h>

typedef unsigned long long u64;
typedef unsigned int u32;

#define HH 512
#define WW 512
#define BATCH 32
#define NPIX (BATCH*HH*WW)
#define NQ (NPIX/4)
#define NWORDS (NPIX/64)
#define WPI (HH*WW/64)      /* u64 words per image = 4096 */
#define WPR (WW/64)         /* u64 words per row = 8 */

#define PS_BLOCKS (BATCH*16)       /* 512: one 32-row strip each */

#define SEARCH_BLOCKS 1024         /* half-word (32 px) per thread */
#define MAIN_BLOCKS 2048           /* 16 px per thread, 4 coalesced sweeps */
#define TOTAL_BLOCKS (SEARCH_BLOCKS + MAIN_BLOCKS)
#define MAIN_TT (MAIN_BLOCKS*256)  /* threads in main partition */

#define WINMASK ((((1ULL<<49)-1)) << 8)   /* dx in [-24,24] of the 64-bit window */

/* workspace layout (bytes) */
#define WS_PART   0          /* double partials[TOTAL_BLOCKS*6] = 144 KiB */
#define WS_TBITS  262144     /* u64[NWORDS] = 1 MiB */
#define WS_BMBITS 1310720    /* u64[NWORDS] = 1 MiB */

__device__ __forceinline__ float hw_exp2(float x) { return __builtin_amdgcn_exp2f(x); }
__device__ __forceinline__ float hw_log2(float x) { return __builtin_amdgcn_logf(x); }

// ============ fused pack + stencil (proven r7 version, unchanged) ============
__global__ __launch_bounds__(256) void pack_stencil_kernel(
        const float4* __restrict__ t4, u64* __restrict__ tbits,
        u64* __restrict__ bmbits) {
    __shared__ u64 lw[36][9];          /* 72B row stride (9th word = pad) */

    const int blk = blockIdx.x;
    const int img = blk >> 4;
    const int strip = blk & 15;
    const int row0 = strip * 32;

    unsigned char* lb = (unsigned char*)lw;
    #pragma unroll
    for (int it = 0; it < 9; ++it) {
        int i = it * 256 + threadIdx.x;    /* 0..2303: 36 rows x 64 bytes */
        int r = i >> 6, c = i & 63;
        int gy = row0 - 2 + r;
        unsigned b = 0;
        if (gy >= 0 && gy < HH) {
            int base = img * (HH*WW/4) + gy * (WW/4) + c * 2;
            float4 lo = t4[base], hi = t4[base + 1];
            b =  (lo.x > 0.5f)       | ((lo.y > 0.5f) << 1)
              | ((lo.z > 0.5f) << 2) | ((lo.w > 0.5f) << 3)
              | ((hi.x > 0.5f) << 4) | ((hi.y > 0.5f) << 5)
              | ((hi.z > 0.5f) << 6) | ((hi.w > 0.5f) << 7);
        }
        lb[r * 72 + c] = (unsigned char)b;
    }
    __syncthreads();

    const int r  = threadIdx.x >> 3;   /* 0..31 owned row */
    const int wc = threadIdx.x & 7;    /* 0..7 word col   */

    u64 w[5][5];
    #pragma unroll
    for (int dr = 0; dr < 5; ++dr)
        #pragma unroll
        for (int dc = 0; dc < 5; ++dc) {
            int cc = wc + dc - 2;
            w[dr][dc] = (cc >= 0 && cc < 8) ? lw[r + dr][cc] : 0ULL;
        }

    u64 ha[5][3];
    #pragma unroll
    for (int rr = 0; rr < 5; ++rr)
        #pragma unroll
        for (int j = 0; j < 3; ++j) {
            u64 C = w[rr][j + 1], L = w[rr][j], R = w[rr][j + 2];
            ha[rr][j] = ((C << 1) | (L >> 63)) & C & ((C >> 1) | (R << 63));
        }

    u64 eg[3][3];
    #pragma unroll
    for (int i = 0; i < 3; ++i)
        #pragma unroll
        for (int j = 0; j < 3; ++j) {
            u64 er = ha[i][j] & ha[i + 1][j] & ha[i + 2][j];
            eg[i][j] = w[i + 1][j + 1] & ~er;
        }

    u64 out = 0ULL;
    #pragma unroll
    for (int i = 0; i < 3; ++i) {
        u64 E = eg[i][1], L = eg[i][0], R = eg[i][2];
        out |= ((E << 1) | (L >> 63)) | E | ((E >> 1) | (R << 63));
    }

    int gw = img * WPI + (row0 + r) * WPR + wc;
    tbits[gw]  = w[2][2];
    bmbits[gw] = out;
}

// nearest set-bit horizontal distance within +/-24 of x0 on one bit-packed row; 99 if none
__device__ __forceinline__ int rowscan(const u64* __restrict__ row, int x0) {
    int s = x0 - 32;
    int wi = s >> 6;
    int sh = s & 63;
    u64 lo = (wi >= 0 && wi < WPR) ? row[wi] : 0ULL;
    u64 hi = ((wi + 1) < WPR) ? row[wi + 1] : 0ULL;
    u64 win = sh ? ((lo >> sh) | (hi << (64 - sh))) : lo;
    win &= WINMASK;
    u64 left = win << 32;
    u64 right = win >> 32;
    int dl = left ? (__builtin_clzll(left) + 1) : 99;
    int dr = right ? __builtin_ctzll(right) : 99;
    return dl < dr ? dl : dr;
}

// full chamfer weight for one non-boundary pixel
__device__ __forceinline__ float search_weight(const u64* __restrict__ img, int pix) {
    const float L2E = 1.44269504f;
    int x0 = pix & (WW - 1);
    int y0 = (pix >> 9) & (HH - 1);
    float best = 1e9f;
    for (int ady = 0; ady <= 24; ++ady) {
        if ((float)ady >= best) break;
        int hd = 99;
        int yU = y0 - ady;
        if (yU >= 0) hd = rowscan(img + yU * WPR, x0);
        int yD = y0 + ady;
        if (ady > 0 && yD < HH) {
            int h2 = rowscan(img + yD * WPR, x0);
            hd = h2 < hd ? h2 : hd;
        }
        if (hd <= 24) {
            float h = (float)hd, ay = (float)ady;
            float mx = fmaxf(h, ay), mn = fminf(h, ay);
            best = fminf(best, mx + 0.4142135f * mn);
        }
    }
    return (best < 1e8f) ? (hw_exp2(best * (-L2E / 3.0f)) + 0.1f) : 0.1f;
}

// ============ fused compute: blocks [0,1024) search, [1024,3072) stream ============
__global__ __launch_bounds__(256, 4) void fused_kernel(
        const float4* __restrict__ x4, const float* __restrict__ x,
        const u64* __restrict__ tbits, const u64* __restrict__ bmbits,
        const float* __restrict__ alpha_p, const float* __restrict__ gamma_p,
        double* __restrict__ partials) {
    __shared__ double red[4][6];

    const float LOGCLIP = 16.11809565f;   // -log(1e-7)
    const float L2E = 1.44269504f;
    const float LN2 = 0.69314718f;

    double d_p = 0.0, d_t = 0.0, d_pt = 0.0, d_f = 0.0, d_b = 0.0, d_bnd = 0.0;

    if (blockIdx.x < SEARCH_BLOCKS) {
        /* ---- search path: one thread per 32-px half-word, dense lanes ---- */
        int h = blockIdx.x * 256 + threadIdx.x;      /* half-word id */
        int wi = h >> 1;
        int sh32 = (h & 1) * 32;
        u32 m = ~(u32)(bmbits[wi] >> sh32);
        u32 twh = (u32)(tbits[wi] >> sh32);
        const u64* img = bmbits + (wi >> 12) * WPI;
        int pixbase = wi * 64 + sh32;
        float acc = 0.f;
        while (m) {
            int b = __builtin_ctz(m);
            m &= m - 1;
            int pix = pixbase + b;
            float xv = x[pix];
            int tb = (int)((twh >> b) & 1u);
            float ax = fabsf(xv);
            float e = hw_exp2(ax * -L2E);
            float l1pe = hw_log2(1.0f + e) * LN2;
            float sp_neg = fmaxf(-xv, 0.0f) + l1pe;
            float sp = tb ? sp_neg : (sp_neg + xv);
            float bnd = fminf(sp, LOGCLIP);
            acc += bnd * search_weight(img, pix);
        }
        d_bnd = (double)acc;
    } else {
        /* ---- streaming path: 16 px/thread over 4 coalesced sweeps ---- */
        const float a = fminf(fmaxf(alpha_p[0], 0.1f), 0.9f);
        const float one_m_a = 1.0f - a;
        const float g = fminf(fmaxf(gamma_p[0], 1.0f), 5.0f);
        const float gr = rintf(g);
        const bool gint = (g == gr);
        const int gi = (int)gr;

        const int q0 = (blockIdx.x - SEARCH_BLOCKS) * 256 + threadIdx.x;
        float4 xv[4];
        u32 tn[4], bn[4];
        #pragma unroll
        for (int j = 0; j < 4; ++j) {
            int q = q0 + j * MAIN_TT;            /* sweep-coalesced */
            xv[j] = x4[q];
            int sh = (q & 15) * 4;
            tn[j] = (u32)((tbits[q >> 4]  >> sh) & 0xfULL);
            bn[j] = (u32)((bmbits[q >> 4] >> sh) & 0xfULL);
        }

        float s_p = 0.f, s_pt = 0.f, s_f = 0.f, s_b = 0.f, s_bnd = 0.f;
        int c_t = 0;

        #pragma unroll
        for (int j = 0; j < 4; ++j) {
            float xs[4] = {xv[j].x, xv[j].y, xv[j].z, xv[j].w};
            #pragma unroll
            for (int k = 0; k < 4; ++k) {
                float xvv = xs[k];
                int tb = (int)((tn[j] >> k) & 1u);
                int bm = (int)((bn[j] >> k) & 1u);

                float ax = fabsf(xvv);
                float e  = hw_exp2(ax * -L2E);             // exp(-|x|)
                float rc = __builtin_amdgcn_rcpf(1.0f + e);
                float p  = (xvv >= 0.0f) ? rc : e * rc;    // sigmoid
                float l1pe = hw_log2(1.0f + e) * LN2;      // log(1+exp(-|x|))
                float sp_neg = fmaxf(-xvv, 0.0f) + l1pe;   // softplus(-x)
                float sp_pos = sp_neg + xvv;               // softplus(x)

                float bce_el = sp_neg + (tb ? 0.025f : 0.975f) * xvv;
                float q95 = 0.95f * p;
                float u   = tb ? (0.975f - q95) : (0.025f + q95);   // 1 - p_t
                float a_t = tb ? a : one_m_a;
                float pw;
                if (gint) {
                    float u2 = u * u;
                    pw = (gi == 1) ? u : (gi == 2) ? u2 : (gi == 3) ? u2 * u
                       : (gi == 4) ? u2 * u2 : u2 * u2 * u;
                } else {
                    pw = hw_exp2(g * hw_log2(u));
                }
                float focal_el = a_t * pw * bce_el;

                float bce2 = tb ? 7.0f * sp_neg : sp_pos;
                float bnd  = fminf(tb ? sp_neg : sp_pos, LOGCLIP);

                s_p   += p;
                c_t   += tb;
                s_pt  += tb ? p : 0.0f;
                s_f   += focal_el;
                s_b   += bce2;
                s_bnd += bm ? bnd : 0.0f;    /* searchers handled by search blocks */
            }
        }
        d_p = s_p; d_t = (double)c_t; d_pt = s_pt; d_f = s_f; d_b = s_b;
        d_bnd = (double)s_bnd * 1.1;
    }

    /* ---- common epilogue: wave shuffle + LDS cross-wave + one write ---- */
    #pragma unroll
    for (int off = 32; off > 0; off >>= 1) {
        d_p   += __shfl_down(d_p, off);
        d_t   += __shfl_down(d_t, off);
        d_pt  += __shfl_down(d_pt, off);
        d_f   += __shfl_down(d_f, off);
        d_b   += __shfl_down(d_b, off);
        d_bnd += __shfl_down(d_bnd, off);
    }
    int lane = threadIdx.x & 63, wid = threadIdx.x >> 6;
    if (lane == 0) {
        red[wid][0] = d_p;  red[wid][1] = d_t;  red[wid][2] = d_pt;
        red[wid][3] = d_f;  red[wid][4] = d_b;  red[wid][5] = d_bnd;
    }
    __syncthreads();
    if (threadIdx.x == 0) {
        #pragma unroll
        for (int i = 0; i < 6; ++i)
            partials[blockIdx.x * 6 + i] = red[0][i] + red[1][i] + red[2][i] + red[3][i];
    }
}

// ============ final reduction + loss assembly ============
__global__ __launch_bounds__(256) void reduce_kernel(const double* __restrict__ partials,
                                                     float* __restrict__ out) {
    double s[6] = {0, 0, 0, 0, 0, 0};
    for (int b = threadIdx.x; b < TOTAL_BLOCKS; b += 256)
        #pragma unroll
        for (int i = 0; i < 6; ++i) s[i] += partials[b * 6 + i];

    #pragma unroll
    for (int off = 32; off > 0; off >>= 1)
        #pragma unroll
        for (int i = 0; i < 6; ++i) s[i] += __shfl_down(s[i], off);

    __shared__ double red[4][6];
    int lane = threadIdx.x & 63, wid = threadIdx.x >> 6;
    if (lane == 0)
        #pragma unroll
        for (int i = 0; i < 6; ++i) red[wid][i] = s[i];
    __syncthreads();

    if (threadIdx.x == 0) {
        double S_p = red[0][0] + red[1][0] + red[2][0] + red[3][0];
        double S_t = red[0][1] + red[1][1] + red[2][1] + red[3][1];
        double S_pt = red[0][2] + red[1][2] + red[2][2] + red[3][2];
        double S_f = red[0][3] + red[1][3] + red[2][3] + red[3][3];
        double S_b = red[0][4] + red[1][4] + red[2][4] + red[3][4];
        double S_bnd = red[0][5] + red[1][5] + red[2][5] + red[3][5];
        const double N = (double)NPIX;
        double inter = S_pt;
        double card = S_p + S_t;
        double dice_score = (2.0 * inter + 1e-6) / fmax(card + 1e-6, 1e-7);
        double dice = (S_t > 0.0) ? (1.0 - dice_score) : 0.0;
        double focal = S_f / N;
        double bce = S_b / N;
        double pos_ratio = S_t / N;
        double da = 0.7 * (1.0 + pos_ratio);
        double db = 0.3 * (2.0 - pos_ratio);
        double fn = S_t - S_pt;
        double fp = (S_p - S_pt) * 3.0;
        double tversky = 1.0 - (S_pt + 1e-6) / (S_pt + da * fn + db * fp + 1e-6);
        double bnd = S_bnd / N;
        out[0] = (float)(0.35 * dice + 0.25 * focal + 0.15 * bce + 0.15 * tversky + 0.1 * bnd);
    }
}

extern "C" void kernel_launch(void* const* d_in, const int* in_sizes, int n_in,
                              void* d_out, int out_size, void* d_ws, size_t ws_size,
                              hipStream_t stream) {
    const float* inputs  = (const float*)d_in[0];
    const float* targets = (const float*)d_in[1];
    const float* alpha_p = (const float*)d_in[2];
    const float* gamma_p = (const float*)d_in[3];
    float* out = (float*)d_out;

    char* ws = (char*)d_ws;
    double* partials = (double*)(ws + WS_PART);
    u64*    tbits    = (u64*)(ws + WS_TBITS);
    u64*    bmbits   = (u64*)(ws + WS_BMBITS);

    pack_stencil_kernel<<<PS_BLOCKS, 256, 0, stream>>>(
        (const float4*)targets, tbits, bmbits);

    fused_kernel<<<TOTAL_BLOCKS, 256, 0, stream>>>(
        (const float4*)inputs, inputs, tbits, bmbits, alpha_p, gamma_p, partials);

    reduce_kernel<<<1, 256, 0, stream>>>(partials, out);
}